// Round 8
// baseline (234.338 us; speedup 1.0000x reference)
//
#include <hip/hip_runtime.h>
#include <hip/hip_fp16.h>

// Problem constants (from reference)
#define NN 100000
#define KK 32
#define DD 128
// remove = floor(32*0.45) = 14 -> keep sorted ranks [14,18), mean of 4

typedef _Float16 v8h __attribute__((ext_vector_type(8)));
typedef _Float16 v4h __attribute__((ext_vector_type(4)));
typedef _Float16 v2h __attribute__((ext_vector_type(2)));
typedef float    v4f __attribute__((ext_vector_type(4)));
typedef int      v2i __attribute__((ext_vector_type(2)));

#define LDH 136   // padded LDS row stride in f16 (128 + 8): 272 B = 17*16 B

// ---------------------------------------------------------------------------
// h layout: 2-way SLICE-MAJOR: h_s[s][n][64] f16, slice s = channels
// [64s, 64s+64). Rows are 128 B = ONE TCP (L1) line -> a row gather is a
// single 128 B line-request (6.4M total; r7 measured this worth -8% vs 64 B).
// slice = blockIdx & 1 -> slice 0 on even XCDs, slice 1 on odd XCDs.
// nbrs/out traffic is nontemporal so the streams don't evict the slice.
//
// r8 change: CE uses __builtin_elementwise_min/max (native v_pk_min/max_f16)
// instead of inline asm. The asm blocks' "=v" outputs forced v_mov pairs
// (measured: VALU-busy-time 2x the 4-op/CE arithmetic across r1/r5/r7);
// native ops are SSA-renameable so the allocator coalesces them away.
// ---------------------------------------------------------------------------

// Kernel 1: h = x @ W^T in f16 via MFMA 16x16x32 (store addressing = 2-slice).
__global__ __launch_bounds__(256)
void gemm_mfma_kernel(const float* __restrict__ x, const float* __restrict__ W,
                      _Float16* __restrict__ h) {
    __shared__ _Float16 w_lds[DD * LDH];
    __shared__ _Float16 x_lds[128 * LDH];

    const int tid = threadIdx.x;
    const int block_row = blockIdx.x * 128;

    {
        const float4* ws = (const float4*)W;
        #pragma unroll
        for (int t = 0; t < 16; ++t) {
            const int fi = tid + 256 * t;
            const int r = fi >> 5, c4 = fi & 31;
            const float4 f = ws[fi];
            v4h p = { (_Float16)f.x, (_Float16)f.y, (_Float16)f.z, (_Float16)f.w };
            *(v4h*)&w_lds[r * LDH + c4 * 4] = p;
        }
    }
    {
        const float4* xs = (const float4*)x;
        #pragma unroll
        for (int t = 0; t < 16; ++t) {
            const int fi = tid + 256 * t;
            const int r = fi >> 5, c4 = fi & 31;
            const int gr = block_row + r;
            float4 f = make_float4(0.f, 0.f, 0.f, 0.f);
            if (gr < NN) f = xs[(size_t)gr * 32 + c4];
            v4h p = { (_Float16)f.x, (_Float16)f.y, (_Float16)f.z, (_Float16)f.w };
            *(v4h*)&x_lds[r * LDH + c4 * 4] = p;
        }
    }
    __syncthreads();

    const int wv   = tid >> 6;
    const int lane = tid & 63;
    const int m    = lane & 15;
    const int quad = lane >> 4;

    const v4f zero = {0.f, 0.f, 0.f, 0.f};
    v4f acc[2][8];
    #pragma unroll
    for (int nt = 0; nt < 2; ++nt)
        #pragma unroll
        for (int ot = 0; ot < 8; ++ot) acc[nt][ot] = zero;

    #pragma unroll
    for (int ks = 0; ks < 4; ++ks) {
        const int kb = ks * 32 + quad * 8;
        const v8h xf0 = *(const v8h*)&x_lds[(wv * 32 + m) * LDH + kb];
        const v8h xf1 = *(const v8h*)&x_lds[(wv * 32 + 16 + m) * LDH + kb];
        #pragma unroll
        for (int ot = 0; ot < 8; ++ot) {
            const v8h wf = *(const v8h*)&w_lds[(ot * 16 + m) * LDH + kb];
            acc[0][ot] = __builtin_amdgcn_mfma_f32_16x16x32_f16(wf, xf0, acc[0][ot], 0, 0, 0);
            acc[1][ot] = __builtin_amdgcn_mfma_f32_16x16x32_f16(wf, xf1, acc[1][ot], 0, 0, 0);
        }
    }

    #pragma unroll
    for (int nt = 0; nt < 2; ++nt) {
        const int xr = block_row + wv * 32 + nt * 16 + m;
        if (xr < NN) {
            #pragma unroll
            for (int ot = 0; ot < 8; ++ot) {
                const v4f a = acc[nt][ot];
                v4h p = { (_Float16)a.x, (_Float16)a.y, (_Float16)a.z, (_Float16)a.w };
                const int c   = ot * 16 + quad * 4;   // global channel of first elem
                const int s   = c >> 6;               // slice 0..1
                const int col = c & 63;               // column within slice
                *(v4h*)&h[((size_t)s * NN + xr) * 64 + col] = p;
            }
        }
    }
}

// ---------------------------------------------------------------------------
// Compile-time Batcher odd-even mergesort network for 16 elements (63 CEs).
// ---------------------------------------------------------------------------
struct CEp { signed char a, b; };
struct Net16 { CEp ce[63]; };

constexpr int oem_merge(CEp* out, int c, int lo, int n, int r) {
    const int m = r * 2;
    if (m < n) {
        c = oem_merge(out, c, lo, n, m);
        c = oem_merge(out, c, lo + r, n, m);
        for (int i = lo + r; i + r < lo + n; i += m) {
            out[c].a = (signed char)i; out[c].b = (signed char)(i + r); ++c;
        }
    } else {
        out[c].a = (signed char)lo; out[c].b = (signed char)(lo + r); ++c;
    }
    return c;
}
constexpr int oem_sort(CEp* out, int c, int lo, int n) {
    if (n > 1) {
        const int m = n / 2;
        c = oem_sort(out, c, lo, m);
        c = oem_sort(out, c, lo + m, m);
        c = oem_merge(out, c, lo, n, 1);
    }
    return c;
}
constexpr Net16 make_net16() {
    Net16 net{};
    (void)oem_sort(net.ce, 0, 0, 16);   // fills exactly 63 CEs
    return net;
}
constexpr Net16 NET16 = make_net16();

// w-index -> v-index map for the final bitonic merge
constexpr int WMAP(int i) { return i < 16 ? i : 47 - i; }

// ---------------------------------------------------------------------------
// Kernel 2: per (row, channel-quad): gather 32 x 8B (4 f16 channels) from the
// slice. 16 lanes x 8 B = one FULL 128 B row = one L1-line request per
// neighbor row. Sort all 4 channels simultaneously with native packed f16
// min/max (v_pk_min_f16 / v_pk_max_f16 via elementwise builtins), trimmed
// mean of ranks 14..17.
// Network: 2 x Batcher-16 (63 CE each) + pruned bitonic merge (44 CE) = 170.
//
// Block = 256 threads = 16 rows x 16 channel-quads; slice = blockIdx & 1.
// nbrs loads / out stores nontemporal (protect resident h in L2).
// ---------------------------------------------------------------------------

// ascending compare-exchange on v-indices (p gets min, q gets max)
#define CEW(p, q) do {                                                  \
    const v2h pa_ = va[p], qa_ = va[q];                                 \
    const v2h pb_ = vb[p], qb_ = vb[q];                                 \
    va[p] = __builtin_elementwise_min(pa_, qa_);                        \
    va[q] = __builtin_elementwise_max(pa_, qa_);                        \
    vb[p] = __builtin_elementwise_min(pb_, qb_);                        \
    vb[q] = __builtin_elementwise_max(pb_, qb_); } while (0)

__global__ __launch_bounds__(256)
void trimmed_mean_kernel(const _Float16* __restrict__ h, const int* __restrict__ nbrs,
                         float* __restrict__ out) {
    __shared__ int s_nbr[16][33];   // +1 pad: distinct write banks

    const int tid      = threadIdx.x;
    const int slice    = blockIdx.x & 1;          // even XCDs: s0, odd XCDs: s1
    const int row_base = (blockIdx.x >> 1) * 16;  // 100000/16 = 6250 exact

    // Load 16 rows x 32 neighbor indices (512 ints) cooperatively,
    // nontemporal to protect the resident h-slice from eviction.
    {
        const v2i v = __builtin_nontemporal_load(
            (const v2i*)(nbrs + (size_t)row_base * KK) + tid);
        const int li = tid * 2;
        const int r = li >> 5, c = li & 31;
        s_nbr[r][c] = v.x; s_nbr[r][c + 1] = v.y;
    }
    __syncthreads();

    const int q   = tid & 15;        // channel quad within slice: [4q, 4q+4)
    const int r   = tid >> 4;        // row within block, 0..15
    const int row = row_base + r;

    // slice base in 8B units; slice row stride = 16 uint2 (64 ch * 2 B = 128 B)
    const uint2* hs = (const uint2*)h + (size_t)slice * NN * 16 + q;

    v2h va[KK];   // channels 4q, 4q+1
    v2h vb[KK];   // channels 4q+2, 4q+3
    #pragma unroll
    for (int k = 0; k < KK; ++k) {
        const int idx = s_nbr[r][k];
        const uint2 u = hs[(size_t)idx * 16];
        va[k] = __builtin_bit_cast(v2h, u.x);
        vb[k] = __builtin_bit_cast(v2h, u.y);
    }

    // Sort both 16-halves ascending (Batcher odd-even mergesort, 63 CE each).
    #pragma unroll
    for (int t = 0; t < 63; ++t) CEW(NET16.ce[t].a, NET16.ce[t].b);
    #pragma unroll
    for (int t = 0; t < 63; ++t) CEW(NET16.ce[t].a + 16, NET16.ce[t].b + 16);

    // Bitonic merge on w = [asc half A, reversed half B], pruned to the
    // middle-4 SET (ranks 14..17 land at w14..w17; internal order irrelevant).
    #pragma unroll
    for (int i = 0; i < 16; ++i) CEW(WMAP(i), WMAP(i + 16));               // j=16
    #pragma unroll
    for (int i = 0; i < 8; ++i) { CEW(WMAP(i), WMAP(i + 8));               // j=8
                                  CEW(WMAP(i + 16), WMAP(i + 24)); }
    #pragma unroll
    for (int i = 8; i < 12; ++i) { CEW(WMAP(i), WMAP(i + 4));              // j=4
                                   CEW(WMAP(i + 8), WMAP(i + 12)); }
    CEW(WMAP(12), WMAP(14)); CEW(WMAP(13), WMAP(15));                      // j=2
    CEW(WMAP(16), WMAP(18)); CEW(WMAP(17), WMAP(19));

    // w14=v[14], w15=v[15], w16=v[31], w17=v[30]
    v4f o;
    o.x = ((float)va[14].x + (float)va[15].x + (float)va[31].x + (float)va[30].x) * 0.25f;
    o.y = ((float)va[14].y + (float)va[15].y + (float)va[31].y + (float)va[30].y) * 0.25f;
    o.z = ((float)vb[14].x + (float)vb[15].x + (float)vb[31].x + (float)vb[30].x) * 0.25f;
    o.w = ((float)vb[14].y + (float)vb[15].y + (float)vb[31].y + (float)vb[30].y) * 0.25f;
    __builtin_nontemporal_store(
        o, (v4f*)(out + (size_t)row * DD + slice * 64) + q);
}

extern "C" void kernel_launch(void* const* d_in, const int* in_sizes, int n_in,
                              void* d_out, int out_size, void* d_ws, size_t ws_size,
                              hipStream_t stream) {
    const float* x    = (const float*)d_in[0];   // (N, 128) fp32
    const float* W    = (const float*)d_in[1];   // (128, 128) fp32
    const int*   nbrs = (const int*)d_in[2];     // (N, 32) int32
    float*       out  = (float*)d_out;           // (N, 128) fp32
    _Float16*    h    = (_Float16*)d_ws;         // scratch: N*128 f16, 2-slice-major

    (void)in_sizes; (void)n_in; (void)out_size; (void)ws_size;

    gemm_mfma_kernel<<<(NN + 127) / 128, 256, 0, stream>>>(x, W, h);       // 782 blocks
    trimmed_mean_kernel<<<(NN / 16) * 2, 256, 0, stream>>>(h, nbrs, out);  // 12500 blocks
}

// Round 9
// 211.216 us; speedup vs baseline: 1.1095x; 1.1095x over previous
//
#include <hip/hip_runtime.h>
#include <hip/hip_fp16.h>

// Problem constants (from reference)
#define NN 100000
#define KK 32
#define DD 128
// remove = floor(32*0.45) = 14 -> keep sorted ranks [14,18), mean of 4

typedef _Float16 v8h __attribute__((ext_vector_type(8)));
typedef _Float16 v4h __attribute__((ext_vector_type(4)));
typedef _Float16 v2h __attribute__((ext_vector_type(2)));
typedef float    v4f __attribute__((ext_vector_type(4)));
typedef int      v2i __attribute__((ext_vector_type(2)));

#define LDH 136   // padded LDS row stride in f16 (128 + 8): 272 B = 17*16 B

// ---------------------------------------------------------------------------
// h layout: 2-way SLICE-MAJOR: h_s[s][n][64] f16, slice s = channels
// [64s, 64s+64). Rows are 128 B = ONE TCP (L1) line -> one line-request per
// gathered row (6.4M total; measured best: r7 = 96.6 us).
// slice = blockIdx & 1 -> slice 0 on even XCDs, slice 1 on odd XCDs.
// nbrs/out traffic is nontemporal so the streams don't evict the slice.
//
// Bottleneck ledger (measured r1/r3/r5/r7/r8):
//  - L2-miss fabric path saturates ~3.0-3.3 TB/s (FETCH/dur invariant);
//    r7 floor = 287 MB / 3.3 TB/s ~ 87 us. THIS is the binder.
//  - real VALU busy ~33 us (VALUBusy derived counter overstates 2x on gfx950:
//    gfx94x SIMD-16 formula vs CDNA4 SIMD-32).
//  - 32 B rows (8-slice) cut FETCH to 62 MB but double request count -> 143 us.
//  - asm CE is optimal: __builtin_elementwise_min/max adds IEEE canonicalize
//    ops (r8: +12 VGPR, -17% occupancy, +26 us).
// ---------------------------------------------------------------------------

// Kernel 1: h = x @ W^T in f16 via MFMA 16x16x32 (store addressing = 2-slice).
__global__ __launch_bounds__(256)
void gemm_mfma_kernel(const float* __restrict__ x, const float* __restrict__ W,
                      _Float16* __restrict__ h) {
    __shared__ _Float16 w_lds[DD * LDH];
    __shared__ _Float16 x_lds[128 * LDH];

    const int tid = threadIdx.x;
    const int block_row = blockIdx.x * 128;

    {
        const float4* ws = (const float4*)W;
        #pragma unroll
        for (int t = 0; t < 16; ++t) {
            const int fi = tid + 256 * t;
            const int r = fi >> 5, c4 = fi & 31;
            const float4 f = ws[fi];
            v4h p = { (_Float16)f.x, (_Float16)f.y, (_Float16)f.z, (_Float16)f.w };
            *(v4h*)&w_lds[r * LDH + c4 * 4] = p;
        }
    }
    {
        const float4* xs = (const float4*)x;
        #pragma unroll
        for (int t = 0; t < 16; ++t) {
            const int fi = tid + 256 * t;
            const int r = fi >> 5, c4 = fi & 31;
            const int gr = block_row + r;
            float4 f = make_float4(0.f, 0.f, 0.f, 0.f);
            if (gr < NN) f = xs[(size_t)gr * 32 + c4];
            v4h p = { (_Float16)f.x, (_Float16)f.y, (_Float16)f.z, (_Float16)f.w };
            *(v4h*)&x_lds[r * LDH + c4 * 4] = p;
        }
    }
    __syncthreads();

    const int wv   = tid >> 6;
    const int lane = tid & 63;
    const int m    = lane & 15;
    const int quad = lane >> 4;

    const v4f zero = {0.f, 0.f, 0.f, 0.f};
    v4f acc[2][8];
    #pragma unroll
    for (int nt = 0; nt < 2; ++nt)
        #pragma unroll
        for (int ot = 0; ot < 8; ++ot) acc[nt][ot] = zero;

    #pragma unroll
    for (int ks = 0; ks < 4; ++ks) {
        const int kb = ks * 32 + quad * 8;
        const v8h xf0 = *(const v8h*)&x_lds[(wv * 32 + m) * LDH + kb];
        const v8h xf1 = *(const v8h*)&x_lds[(wv * 32 + 16 + m) * LDH + kb];
        #pragma unroll
        for (int ot = 0; ot < 8; ++ot) {
            const v8h wf = *(const v8h*)&w_lds[(ot * 16 + m) * LDH + kb];
            acc[0][ot] = __builtin_amdgcn_mfma_f32_16x16x32_f16(wf, xf0, acc[0][ot], 0, 0, 0);
            acc[1][ot] = __builtin_amdgcn_mfma_f32_16x16x32_f16(wf, xf1, acc[1][ot], 0, 0, 0);
        }
    }

    #pragma unroll
    for (int nt = 0; nt < 2; ++nt) {
        const int xr = block_row + wv * 32 + nt * 16 + m;
        if (xr < NN) {
            #pragma unroll
            for (int ot = 0; ot < 8; ++ot) {
                const v4f a = acc[nt][ot];
                v4h p = { (_Float16)a.x, (_Float16)a.y, (_Float16)a.z, (_Float16)a.w };
                const int c   = ot * 16 + quad * 4;   // global channel of first elem
                const int s   = c >> 6;               // slice 0..1
                const int col = c & 63;               // column within slice
                *(v4h*)&h[((size_t)s * NN + xr) * 64 + col] = p;
            }
        }
    }
}

// ---------------------------------------------------------------------------
// Compile-time Batcher odd-even mergesort network for 16 elements (63 CEs).
// ---------------------------------------------------------------------------
struct CEp { signed char a, b; };
struct Net16 { CEp ce[63]; };

constexpr int oem_merge(CEp* out, int c, int lo, int n, int r) {
    const int m = r * 2;
    if (m < n) {
        c = oem_merge(out, c, lo, n, m);
        c = oem_merge(out, c, lo + r, n, m);
        for (int i = lo + r; i + r < lo + n; i += m) {
            out[c].a = (signed char)i; out[c].b = (signed char)(i + r); ++c;
        }
    } else {
        out[c].a = (signed char)lo; out[c].b = (signed char)(lo + r); ++c;
    }
    return c;
}
constexpr int oem_sort(CEp* out, int c, int lo, int n) {
    if (n > 1) {
        const int m = n / 2;
        c = oem_sort(out, c, lo, m);
        c = oem_sort(out, c, lo + m, m);
        c = oem_merge(out, c, lo, n, 1);
    }
    return c;
}
constexpr Net16 make_net16() {
    Net16 net{};
    (void)oem_sort(net.ce, 0, 0, 16);   // fills exactly 63 CEs
    return net;
}
constexpr Net16 NET16 = make_net16();

// w-index -> v-index map for the final bitonic merge
constexpr int WMAP(int i) { return i < 16 ? i : 47 - i; }

// ---------------------------------------------------------------------------
// Kernel 2: per (row, channel-quad): gather 32 x 8B (4 f16 channels) from the
// slice. 16 lanes x 8 B = one FULL 128 B row = one L1-line request per
// neighbor row. Sort all 4 channels simultaneously with forced
// v_pk_min/max_f16 (inline asm; builtins add IEEE canonicalize ops),
// trimmed mean of ranks 14..17.
// Network: 2 x Batcher-16 (63 CE each) + pruned bitonic merge (44 CE) = 170.
//
// Block = 256 threads = 16 rows x 16 channel-quads; slice = blockIdx & 1.
// nbrs loads / out stores nontemporal (protect resident h in L2).
// ---------------------------------------------------------------------------
#define PKMIN(d, s0, s1) asm("v_pk_min_f16 %0, %1, %2" : "=v"(d) : "v"(s0), "v"(s1))
#define PKMAX(d, s0, s1) asm("v_pk_max_f16 %0, %1, %2" : "=v"(d) : "v"(s0), "v"(s1))

// ascending compare-exchange on v-indices (p gets min, q gets max)
#define CEW(p, q) do {                                                  \
    v2h na_, xa_, nb_, xb_;                                             \
    PKMIN(na_, va[p], va[q]); PKMAX(xa_, va[p], va[q]);                 \
    PKMIN(nb_, vb[p], vb[q]); PKMAX(xb_, vb[p], vb[q]);                 \
    va[p] = na_; va[q] = xa_; vb[p] = nb_; vb[q] = xb_; } while (0)

__global__ __launch_bounds__(256)
void trimmed_mean_kernel(const _Float16* __restrict__ h, const int* __restrict__ nbrs,
                         float* __restrict__ out) {
    __shared__ int s_nbr[16][33];   // +1 pad: distinct write banks

    const int tid      = threadIdx.x;
    const int slice    = blockIdx.x & 1;          // even XCDs: s0, odd XCDs: s1
    const int row_base = (blockIdx.x >> 1) * 16;  // 100000/16 = 6250 exact

    // Load 16 rows x 32 neighbor indices (512 ints) cooperatively,
    // nontemporal to protect the resident h-slice from eviction.
    {
        const v2i v = __builtin_nontemporal_load(
            (const v2i*)(nbrs + (size_t)row_base * KK) + tid);
        const int li = tid * 2;
        const int r = li >> 5, c = li & 31;
        s_nbr[r][c] = v.x; s_nbr[r][c + 1] = v.y;
    }
    __syncthreads();

    const int q   = tid & 15;        // channel quad within slice: [4q, 4q+4)
    const int r   = tid >> 4;        // row within block, 0..15
    const int row = row_base + r;

    // slice base in 8B units; slice row stride = 16 uint2 (64 ch * 2 B = 128 B)
    const uint2* hs = (const uint2*)h + (size_t)slice * NN * 16 + q;

    v2h va[KK];   // channels 4q, 4q+1
    v2h vb[KK];   // channels 4q+2, 4q+3
    #pragma unroll
    for (int k = 0; k < KK; ++k) {
        const int idx = s_nbr[r][k];
        const uint2 u = hs[(size_t)idx * 16];
        va[k] = __builtin_bit_cast(v2h, u.x);
        vb[k] = __builtin_bit_cast(v2h, u.y);
    }

    // Sort both 16-halves ascending (Batcher odd-even mergesort, 63 CE each).
    #pragma unroll
    for (int t = 0; t < 63; ++t) CEW(NET16.ce[t].a, NET16.ce[t].b);
    #pragma unroll
    for (int t = 0; t < 63; ++t) CEW(NET16.ce[t].a + 16, NET16.ce[t].b + 16);

    // Bitonic merge on w = [asc half A, reversed half B], pruned to the
    // middle-4 SET (ranks 14..17 land at w14..w17; internal order irrelevant).
    #pragma unroll
    for (int i = 0; i < 16; ++i) CEW(WMAP(i), WMAP(i + 16));               // j=16
    #pragma unroll
    for (int i = 0; i < 8; ++i) { CEW(WMAP(i), WMAP(i + 8));               // j=8
                                  CEW(WMAP(i + 16), WMAP(i + 24)); }
    #pragma unroll
    for (int i = 8; i < 12; ++i) { CEW(WMAP(i), WMAP(i + 4));              // j=4
                                   CEW(WMAP(i + 8), WMAP(i + 12)); }
    CEW(WMAP(12), WMAP(14)); CEW(WMAP(13), WMAP(15));                      // j=2
    CEW(WMAP(16), WMAP(18)); CEW(WMAP(17), WMAP(19));

    // w14=v[14], w15=v[15], w16=v[31], w17=v[30]
    v4f o;
    o.x = ((float)va[14].x + (float)va[15].x + (float)va[31].x + (float)va[30].x) * 0.25f;
    o.y = ((float)va[14].y + (float)va[15].y + (float)va[31].y + (float)va[30].y) * 0.25f;
    o.z = ((float)vb[14].x + (float)vb[15].x + (float)vb[31].x + (float)vb[30].x) * 0.25f;
    o.w = ((float)vb[14].y + (float)vb[15].y + (float)vb[31].y + (float)vb[30].y) * 0.25f;
    __builtin_nontemporal_store(
        o, (v4f*)(out + (size_t)row * DD + slice * 64) + q);
}

extern "C" void kernel_launch(void* const* d_in, const int* in_sizes, int n_in,
                              void* d_out, int out_size, void* d_ws, size_t ws_size,
                              hipStream_t stream) {
    const float* x    = (const float*)d_in[0];   // (N, 128) fp32
    const float* W    = (const float*)d_in[1];   // (128, 128) fp32
    const int*   nbrs = (const int*)d_in[2];     // (N, 32) int32
    float*       out  = (float*)d_out;           // (N, 128) fp32
    _Float16*    h    = (_Float16*)d_ws;         // scratch: N*128 f16, 2-slice-major

    (void)in_sizes; (void)n_in; (void)out_size; (void)ws_size;

    gemm_mfma_kernel<<<(NN + 127) / 128, 256, 0, stream>>>(x, W, h);       // 782 blocks
    trimmed_mean_kernel<<<(NN / 16) * 2, 256, 0, stream>>>(h, nbrs, out);  // 12500 blocks
}

// Round 10
// 205.587 us; speedup vs baseline: 1.1398x; 1.0274x over previous
//
#include <hip/hip_runtime.h>
#include <hip/hip_fp16.h>

// Problem constants (from reference)
#define NN 100000
#define KK 32
#define DD 128
// remove = floor(32*0.45) = 14 -> keep sorted ranks [14,18), mean of 4

typedef _Float16 v8h __attribute__((ext_vector_type(8)));
typedef _Float16 v4h __attribute__((ext_vector_type(4)));
typedef _Float16 v2h __attribute__((ext_vector_type(2)));
typedef float    v4f __attribute__((ext_vector_type(4)));
typedef float    v2f __attribute__((ext_vector_type(2)));

#define LDH 136   // padded LDS row stride in f16 (128 + 8): 272 B = 17*16 B

// ---------------------------------------------------------------------------
// h layout: 2-way SLICE-MAJOR: h_s[s][n][64] f16, slice s = channels
// [64s, 64s+64). Rows are 128 B = ONE TCP line -> one line-request per
// gathered row (6.4M total, the provable minimum N*K*256B/128B).
// slice = blockIdx & 1. nbrs/out traffic nontemporal.
//
// r10 experiment (discriminates latency-vs-VALU-vs-fabric):
//  - 2 ch/thread (32 data VGPRs instead of 64): 32 lanes/row x 4 B still
//    coalesces to one 128 B request per row -> SAME requests/FETCH as r7,
//    but occupancy 5.3 -> 8 waves/SIMD for ~1.5x outstanding misses.
//  - 32-bit voffset gathers (saddr form): off = (idx<<7)|q*4, uniform base.
// Ledger: VALU count not binding (r1 vs r5); requests at minimum (r7);
// asm CE optimal (r8 regression); 8-slice residency trade loses (r3).
// ---------------------------------------------------------------------------

// Kernel 1: h = x @ W^T in f16 via MFMA 16x16x32 (store addressing = 2-slice).
__global__ __launch_bounds__(256)
void gemm_mfma_kernel(const float* __restrict__ x, const float* __restrict__ W,
                      _Float16* __restrict__ h) {
    __shared__ _Float16 w_lds[DD * LDH];
    __shared__ _Float16 x_lds[128 * LDH];

    const int tid = threadIdx.x;
    const int block_row = blockIdx.x * 128;

    {
        const float4* ws = (const float4*)W;
        #pragma unroll
        for (int t = 0; t < 16; ++t) {
            const int fi = tid + 256 * t;
            const int r = fi >> 5, c4 = fi & 31;
            const float4 f = ws[fi];
            v4h p = { (_Float16)f.x, (_Float16)f.y, (_Float16)f.z, (_Float16)f.w };
            *(v4h*)&w_lds[r * LDH + c4 * 4] = p;
        }
    }
    {
        const float4* xs = (const float4*)x;
        #pragma unroll
        for (int t = 0; t < 16; ++t) {
            const int fi = tid + 256 * t;
            const int r = fi >> 5, c4 = fi & 31;
            const int gr = block_row + r;
            float4 f = make_float4(0.f, 0.f, 0.f, 0.f);
            if (gr < NN) f = xs[(size_t)gr * 32 + c4];
            v4h p = { (_Float16)f.x, (_Float16)f.y, (_Float16)f.z, (_Float16)f.w };
            *(v4h*)&x_lds[r * LDH + c4 * 4] = p;
        }
    }
    __syncthreads();

    const int wv   = tid >> 6;
    const int lane = tid & 63;
    const int m    = lane & 15;
    const int quad = lane >> 4;

    const v4f zero = {0.f, 0.f, 0.f, 0.f};
    v4f acc[2][8];
    #pragma unroll
    for (int nt = 0; nt < 2; ++nt)
        #pragma unroll
        for (int ot = 0; ot < 8; ++ot) acc[nt][ot] = zero;

    #pragma unroll
    for (int ks = 0; ks < 4; ++ks) {
        const int kb = ks * 32 + quad * 8;
        const v8h xf0 = *(const v8h*)&x_lds[(wv * 32 + m) * LDH + kb];
        const v8h xf1 = *(const v8h*)&x_lds[(wv * 32 + 16 + m) * LDH + kb];
        #pragma unroll
        for (int ot = 0; ot < 8; ++ot) {
            const v8h wf = *(const v8h*)&w_lds[(ot * 16 + m) * LDH + kb];
            acc[0][ot] = __builtin_amdgcn_mfma_f32_16x16x32_f16(wf, xf0, acc[0][ot], 0, 0, 0);
            acc[1][ot] = __builtin_amdgcn_mfma_f32_16x16x32_f16(wf, xf1, acc[1][ot], 0, 0, 0);
        }
    }

    #pragma unroll
    for (int nt = 0; nt < 2; ++nt) {
        const int xr = block_row + wv * 32 + nt * 16 + m;
        if (xr < NN) {
            #pragma unroll
            for (int ot = 0; ot < 8; ++ot) {
                const v4f a = acc[nt][ot];
                v4h p = { (_Float16)a.x, (_Float16)a.y, (_Float16)a.z, (_Float16)a.w };
                const int c   = ot * 16 + quad * 4;   // global channel of first elem
                const int s   = c >> 6;               // slice 0..1
                const int col = c & 63;               // column within slice
                *(v4h*)&h[((size_t)s * NN + xr) * 64 + col] = p;
            }
        }
    }
}

// ---------------------------------------------------------------------------
// Compile-time Batcher odd-even mergesort network for 16 elements (63 CEs).
// ---------------------------------------------------------------------------
struct CEp { signed char a, b; };
struct Net16 { CEp ce[63]; };

constexpr int oem_merge(CEp* out, int c, int lo, int n, int r) {
    const int m = r * 2;
    if (m < n) {
        c = oem_merge(out, c, lo, n, m);
        c = oem_merge(out, c, lo + r, n, m);
        for (int i = lo + r; i + r < lo + n; i += m) {
            out[c].a = (signed char)i; out[c].b = (signed char)(i + r); ++c;
        }
    } else {
        out[c].a = (signed char)lo; out[c].b = (signed char)(lo + r); ++c;
    }
    return c;
}
constexpr int oem_sort(CEp* out, int c, int lo, int n) {
    if (n > 1) {
        const int m = n / 2;
        c = oem_sort(out, c, lo, m);
        c = oem_sort(out, c, lo + m, m);
        c = oem_merge(out, c, lo, n, 1);
    }
    return c;
}
constexpr Net16 make_net16() {
    Net16 net{};
    (void)oem_sort(net.ce, 0, 0, 16);   // fills exactly 63 CEs
    return net;
}
constexpr Net16 NET16 = make_net16();

// w-index -> v-index map for the final bitonic merge
constexpr int WMAP(int i) { return i < 16 ? i : 47 - i; }

// ---------------------------------------------------------------------------
// Kernel 2: per (row, channel-pair): gather 32 x 4B (2 f16 channels) from the
// slice. 32 lanes x 4 B = one FULL 128 B row = one line request per neighbor
// row (same 6.4M total as r7). Sort both channels simultaneously with forced
// v_pk_min/max_f16 (inline asm), trimmed mean of ranks 14..17.
// Network: 2 x Batcher-16 (63 CE each) + pruned bitonic merge (44 CE) = 170.
//
// Block = 256 threads = 8 rows x 32 channel-pairs; slice = blockIdx & 1.
// 32 data VGPRs -> target 8 waves/SIMD (100% occupancy) for latency hiding.
// ---------------------------------------------------------------------------
#define PKMIN(d, s0, s1) asm("v_pk_min_f16 %0, %1, %2" : "=v"(d) : "v"(s0), "v"(s1))
#define PKMAX(d, s0, s1) asm("v_pk_max_f16 %0, %1, %2" : "=v"(d) : "v"(s0), "v"(s1))

// ascending compare-exchange on v-indices (p gets min, q gets max)
#define CEW(p, q) do {                                                  \
    v2h n_, x_;                                                         \
    PKMIN(n_, va[p], va[q]); PKMAX(x_, va[p], va[q]);                   \
    va[p] = n_; va[q] = x_; } while (0)

__global__ __launch_bounds__(256)
void trimmed_mean_kernel(const _Float16* __restrict__ h, const int* __restrict__ nbrs,
                         float* __restrict__ out) {
    __shared__ int s_nbr[8][33];    // +1 pad: distinct write banks

    const int tid      = threadIdx.x;
    const int slice    = blockIdx.x & 1;          // even XCDs: s0, odd XCDs: s1
    const int row_base = (blockIdx.x >> 1) * 8;   // 100000/8 = 12500 exact

    // Load 8 rows x 32 neighbor indices (256 ints) cooperatively,
    // nontemporal to protect the resident h-slice from eviction.
    s_nbr[tid >> 5][tid & 31] =
        __builtin_nontemporal_load(nbrs + (size_t)row_base * KK + tid);
    __syncthreads();

    const int q   = tid & 31;        // channel pair within slice: [2q, 2q+2)
    const int r   = tid >> 5;        // row within block, 0..7
    const int row = row_base + r;

    // Uniform 64-bit base + per-lane 32-bit byte offset (saddr-form gathers):
    // off = idx*128 + q*4  (max 12.8M, fits u32)
    const char* base = (const char*)h + (size_t)slice * NN * 128;
    const unsigned int qoff = (unsigned int)q * 4u;

    v2h va[KK];   // channels 2q, 2q+1
    #pragma unroll
    for (int k = 0; k < KK; ++k) {
        const unsigned int idx = (unsigned int)s_nbr[r][k];
        const unsigned int off = (idx << 7) | qoff;
        va[k] = __builtin_bit_cast(v2h, *(const unsigned int*)(base + off));
    }

    // Sort both 16-halves ascending (Batcher odd-even mergesort, 63 CE each).
    #pragma unroll
    for (int t = 0; t < 63; ++t) CEW(NET16.ce[t].a, NET16.ce[t].b);
    #pragma unroll
    for (int t = 0; t < 63; ++t) CEW(NET16.ce[t].a + 16, NET16.ce[t].b + 16);

    // Bitonic merge on w = [asc half A, reversed half B], pruned to the
    // middle-4 SET (ranks 14..17 land at w14..w17; internal order irrelevant).
    #pragma unroll
    for (int i = 0; i < 16; ++i) CEW(WMAP(i), WMAP(i + 16));               // j=16
    #pragma unroll
    for (int i = 0; i < 8; ++i) { CEW(WMAP(i), WMAP(i + 8));               // j=8
                                  CEW(WMAP(i + 16), WMAP(i + 24)); }
    #pragma unroll
    for (int i = 8; i < 12; ++i) { CEW(WMAP(i), WMAP(i + 4));              // j=4
                                   CEW(WMAP(i + 8), WMAP(i + 12)); }
    CEW(WMAP(12), WMAP(14)); CEW(WMAP(13), WMAP(15));                      // j=2
    CEW(WMAP(16), WMAP(18)); CEW(WMAP(17), WMAP(19));

    // w14=v[14], w15=v[15], w16=v[31], w17=v[30]
    v2f o;
    o.x = ((float)va[14].x + (float)va[15].x + (float)va[31].x + (float)va[30].x) * 0.25f;
    o.y = ((float)va[14].y + (float)va[15].y + (float)va[31].y + (float)va[30].y) * 0.25f;
    __builtin_nontemporal_store(
        o, (v2f*)(out + (size_t)row * DD + slice * 64) + q);
}

extern "C" void kernel_launch(void* const* d_in, const int* in_sizes, int n_in,
                              void* d_out, int out_size, void* d_ws, size_t ws_size,
                              hipStream_t stream) {
    const float* x    = (const float*)d_in[0];   // (N, 128) fp32
    const float* W    = (const float*)d_in[1];   // (128, 128) fp32
    const int*   nbrs = (const int*)d_in[2];     // (N, 32) int32
    float*       out  = (float*)d_out;           // (N, 128) fp32
    _Float16*    h    = (_Float16*)d_ws;         // scratch: N*128 f16, 2-slice-major

    (void)in_sizes; (void)n_in; (void)out_size; (void)ws_size;

    gemm_mfma_kernel<<<(NN + 127) / 128, 256, 0, stream>>>(x, W, h);       // 782 blocks
    trimmed_mean_kernel<<<(NN / 8) * 2, 256, 0, stream>>>(h, nbrs, out);   // 25000 blocks
}